// Round 1
// baseline (1591.799 us; speedup 1.0000x reference)
//
#include <hip/hip_runtime.h>
#include <hip/hip_fp16.h>

#define NSENS 4
#define NB    64
#define LIN   2048
#define C1N   32
#define LP1   512
#define C2N   64
#define SEQ   256
#define DM    64
#define H1S   516

#define DOT64(res, xa, wp) { \
  float _a0=0.f,_a1=0.f,_a2=0.f,_a3=0.f; \
  _Pragma("unroll") \
  for (int _c = 0; _c < 64; _c += 4) { \
    _a0 = fmaf((xa)[_c],   (wp)[_c],   _a0); \
    _a1 = fmaf((xa)[_c+1], (wp)[_c+1], _a1); \
    _a2 = fmaf((xa)[_c+2], (wp)[_c+2], _a2); \
    _a3 = fmaf((xa)[_c+3], (wp)[_c+3], _a3); \
  } \
  (res) = (_a0+_a1)+(_a2+_a3); \
}

// ------------------------- conv branch kernel -------------------------
__global__ __launch_bounds__(256) void conv_kernel(
    const float* __restrict__ sens,
    const float* __restrict__ c1w, const float* __restrict__ c1b,
    const float* __restrict__ bn1g, const float* __restrict__ bn1b,
    const float* __restrict__ c2w, const float* __restrict__ c2b,
    const float* __restrict__ bn2g, const float* __restrict__ bn2b,
    float* __restrict__ x0)
{
  const int bid = blockIdx.x;
  const int s = bid >> 6, b = bid & 63;
  const int tid = threadIdx.x;
  __shared__ __half h1p[C1N][H1S];          // conv1 result, halo-padded: [c][l+1], l in [-1,512]
  __shared__ float w2s[C1N*3*C2N];          // conv2 weights re-laid [ci][k][co]

  for (int i = tid; i < C1N*3*C2N; i += 256) {
    int co = i & 63; int rem = i >> 6; int k = rem % 3; int ci = rem / 3;
    w2s[(ci*3 + k)*64 + co] = c2w[((s*C2N + co)*C1N + ci)*3 + k];
  }

  const float* xg = sens + (size_t)(s*NB + b)*LIN;
  const float bnr = rsqrtf(1.0f + 1e-5f);

  // conv1 (k=5, stride2, pad2) + bn + relu + maxpool2 -> h1p (fp16)
  {
    const int c = tid & 31;
    const int l0 = tid >> 5;
    const float w0 = c1w[(s*C1N + c)*5 + 0];
    const float w1 = c1w[(s*C1N + c)*5 + 1];
    const float w2 = c1w[(s*C1N + c)*5 + 2];
    const float w3 = c1w[(s*C1N + c)*5 + 3];
    const float w4 = c1w[(s*C1N + c)*5 + 4];
    const float cb = c1b[s*C1N + c];
    const float sc = bn1g[s*C1N + c]*bnr;
    const float bt = bn1b[s*C1N + c];
    for (int l = l0; l < LP1; l += 8) {
      const int base = 4*l;
      float xm2 = (base-2 >= 0) ? xg[base-2] : 0.f;
      float xm1 = (base-1 >= 0) ? xg[base-1] : 0.f;
      float x0v = xg[base+0];
      float x1v = xg[base+1];
      float x2v = xg[base+2];
      float x3v = xg[base+3];
      float x4v = (base+4 < LIN) ? xg[base+4] : 0.f;
      float y0 = w0*xm2 + w1*xm1 + w2*x0v + w3*x1v + w4*x2v;   // pos 2l
      float y1 = w0*x0v + w1*x1v + w2*x2v + w3*x3v + w4*x4v;   // pos 2l+1
      y0 = (y0 + cb)*sc + bt;
      y1 = (y1 + cb)*sc + bt;
      h1p[c][l+1] = __float2half(fmaxf(fmaxf(y0, y1), 0.f));
      if (l == 0)      h1p[c][0]      = __float2half(0.f);
      if (l == LP1-1)  h1p[c][LP1+1]  = __float2half(0.f);
    }
  }
  __syncthreads();

  // conv2 (k=3, stride1, pad1) + bn + relu + maxpool2 + pos-enc -> x0 [bid][r][d]
  const int rg = tid & 31, cg = tid >> 5;
  const int c0 = cg*8;
  float cb2[8], sc2[8], bt2[8];
  #pragma unroll
  for (int cc = 0; cc < 8; ++cc) {
    cb2[cc] = c2b[s*C2N + c0 + cc];
    sc2[cc] = bn2g[s*C2N + c0 + cc]*bnr;
    bt2[cc] = bn2b[s*C2N + c0 + cc];
  }
  for (int it = 0; it < 4; ++it) {
    const int rA = 64*it + rg;
    const int rB = rA + 32;
    float acc[2][2][8] = {};
    for (int ci = 0; ci < C1N; ++ci) {
      const __half2 a01 = *(const __half2*)&h1p[ci][2*rA];
      const __half2 a23 = *(const __half2*)&h1p[ci][2*rA+2];
      const __half2 b01 = *(const __half2*)&h1p[ci][2*rB];
      const __half2 b23 = *(const __half2*)&h1p[ci][2*rB+2];
      const float hA[4] = { __low2float(a01), __high2float(a01), __low2float(a23), __high2float(a23) };
      const float hB[4] = { __low2float(b01), __high2float(b01), __low2float(b23), __high2float(b23) };
      #pragma unroll
      for (int k = 0; k < 3; ++k) {
        const float4 wv0 = *(const float4*)&w2s[(ci*3+k)*64 + c0];
        const float4 wv1 = *(const float4*)&w2s[(ci*3+k)*64 + c0 + 4];
        const float wr[8] = {wv0.x, wv0.y, wv0.z, wv0.w, wv1.x, wv1.y, wv1.z, wv1.w};
        #pragma unroll
        for (int p = 0; p < 2; ++p) {
          const float xa = hA[k+p];
          const float xb = hB[k+p];
          #pragma unroll
          for (int cc = 0; cc < 8; ++cc) {
            acc[0][p][cc] = fmaf(wr[cc], xa, acc[0][p][cc]);
            acc[1][p][cc] = fmaf(wr[cc], xb, acc[1][p][cc]);
          }
        }
      }
    }
    #pragma unroll
    for (int rr = 0; rr < 2; ++rr) {
      const int r = rr ? rB : rA;
      float* outp = x0 + ((size_t)bid*SEQ + r)*DM + c0;
      #pragma unroll
      for (int cc = 0; cc < 8; ++cc) {
        float v0 = (acc[rr][0][cc] + cb2[cc])*sc2[cc] + bt2[cc];
        float v1 = (acc[rr][1][cc] + cb2[cc])*sc2[cc] + bt2[cc];
        float v = fmaxf(fmaxf(v0, v1), 0.f);
        const int d = c0 + cc;
        const float ang = (float)r * __expf(-0.14391156463f*(float)(d & ~1)); // ln(1e4)/64
        const float pe = (d & 1) ? cosf(ang) : sinf(ang);
        outp[cc] = v + pe;
      }
    }
  }
}

// ------------------------- transformer kernel -------------------------
__global__ __launch_bounds__(256) void tx_kernel(
  const float* __restrict__ x0, float* __restrict__ nf,
  const float* __restrict__ wqkv, const float* __restrict__ bqkv,
  const float* __restrict__ wo, const float* __restrict__ bo,
  const float* __restrict__ ln1g, const float* __restrict__ ln1b,
  const float* __restrict__ fw1, const float* __restrict__ fb1,
  const float* __restrict__ fw2, const float* __restrict__ fb2,
  const float* __restrict__ ln2g, const float* __restrict__ ln2b)
{
  const int bid = blockIdx.x;
  const int s = bid >> 6, b = bid & 63;
  const int t = threadIdx.x;           // one thread per sequence row
  __shared__ float Ksh[SEQ*8];
  __shared__ float Vsh[SEQ*8];
  __shared__ __half tbuf[DM*SEQ];      // transposed scratch [c][t]

  float xr[DM];
  {
    const float4* xp = (const float4*)(x0 + ((size_t)bid*SEQ + t)*DM);
    #pragma unroll
    for (int c = 0; c < DM/4; ++c) {
      float4 v = xp[c];
      xr[4*c] = v.x; xr[4*c+1] = v.y; xr[4*c+2] = v.z; xr[4*c+3] = v.w;
    }
  }

  for (int layer = 0; layer < 2; ++layer) {
    const int wi = s*2 + layer;
    const float* Wq  = wqkv + (size_t)wi*192*64;
    const float* Bq  = bqkv + wi*192;
    const float* Wo  = wo   + (size_t)wi*64*64;
    const float* Bo  = bo   + wi*64;
    const float* G1  = ln1g + wi*64;  const float* B1 = ln1b + wi*64;
    const float* W1  = fw1  + (size_t)wi*256*64;  const float* Bf1 = fb1 + wi*256;
    const float* W2  = fw2  + (size_t)wi*64*256;  const float* Bf2 = fb2 + wi*64;
    const float* G2  = ln2g + wi*64;  const float* B2 = ln2b + wi*64;
    const float qs = 0.35355339059327373f * 1.4426950408889634f;  // 1/sqrt(8) * log2(e)

    // ---- multi-head attention, one head at a time ----
    for (int h = 0; h < 8; ++h) {
      float q[8], kk[8], vv[8];
      #pragma unroll
      for (int d = 0; d < 8; ++d) {
        const float* wq_ = Wq + (h*8+d)*64;
        const float* wk_ = Wq + (64 + h*8+d)*64;
        const float* wv_ = Wq + (128 + h*8+d)*64;
        float qd, kd, vd;
        DOT64(qd, xr, wq_);
        DOT64(kd, xr, wk_);
        DOT64(vd, xr, wv_);
        q[d]  = (qd + Bq[h*8+d]) * qs;
        kk[d] = kd + Bq[64 + h*8+d];
        vv[d] = vd + Bq[128 + h*8+d];
      }
      __syncthreads();   // prior head's readers are done
      {
        float4* kp = (float4*)&Ksh[t*8];
        kp[0] = make_float4(kk[0],kk[1],kk[2],kk[3]);
        kp[1] = make_float4(kk[4],kk[5],kk[6],kk[7]);
        float4* vp = (float4*)&Vsh[t*8];
        vp[0] = make_float4(vv[0],vv[1],vv[2],vv[3]);
        vp[1] = make_float4(vv[4],vv[5],vv[6],vv[7]);
      }
      __syncthreads();   // K/V ready
      float lsum = 0.f;
      float acc[8] = {0.f,0.f,0.f,0.f,0.f,0.f,0.f,0.f};
      #pragma unroll 2
      for (int j = 0; j < SEQ; ++j) {
        const float4 k0 = *(const float4*)&Ksh[j*8];
        const float4 k1 = *(const float4*)&Ksh[j*8+4];
        float sc = (fmaf(q[0],k0.x, q[1]*k0.y) + fmaf(q[2],k0.z, q[3]*k0.w))
                 + (fmaf(q[4],k1.x, q[5]*k1.y) + fmaf(q[6],k1.z, q[7]*k1.w));
        float p = exp2f(sc);          // scores bounded (~|4|) -> max-free softmax is safe
        const float4 v0 = *(const float4*)&Vsh[j*8];
        const float4 v1 = *(const float4*)&Vsh[j*8+4];
        lsum += p;
        acc[0] = fmaf(p, v0.x, acc[0]); acc[1] = fmaf(p, v0.y, acc[1]);
        acc[2] = fmaf(p, v0.z, acc[2]); acc[3] = fmaf(p, v0.w, acc[3]);
        acc[4] = fmaf(p, v1.x, acc[4]); acc[5] = fmaf(p, v1.y, acc[5]);
        acc[6] = fmaf(p, v1.z, acc[6]); acc[7] = fmaf(p, v1.w, acc[7]);
      }
      const float inv = 1.0f / lsum;
      #pragma unroll
      for (int d = 0; d < 8; ++d)
        tbuf[(h*8+d)*SEQ + t] = __float2half(acc[d]*inv);
    }

    // ---- O-projection + residual + LN1 (own column only; no sync needed) ----
    {
      float a[64];
      #pragma unroll
      for (int k = 0; k < 64; ++k) a[k] = __half2float(tbuf[k*SEQ + t]);
      float sum = 0.f, sq = 0.f;
      #pragma unroll
      for (int c = 0; c < 64; ++c) {
        const float* w = Wo + c*64;
        float d_;
        DOT64(d_, a, w);
        float y = d_ + Bo[c] + xr[c];
        sum += y; sq = fmaf(y, y, sq);
        tbuf[c*SEQ + t] = __float2half(y);
      }
      const float mean = sum * (1.0f/64.0f);
      const float var  = sq * (1.0f/64.0f) - mean*mean;
      const float rstd = rsqrtf(var + 1e-5f);
      #pragma unroll
      for (int c = 0; c < 64; ++c)
        xr[c] = (__half2float(tbuf[c*SEQ + t]) - mean)*rstd*G1[c] + B1[c];
    }

    // ---- FF (64->256 gelu ->64) + residual + LN2 ----
    {
      float ff[64];
      #pragma unroll
      for (int c = 0; c < 64; ++c) ff[c] = 0.f;
      for (int ch = 0; ch < 16; ++ch) {
        float g[16];
        #pragma unroll
        for (int i = 0; i < 16; ++i) {
          const float* w = W1 + (ch*16 + i)*64;
          float d_;
          DOT64(d_, xr, w);
          const float hv = d_ + Bf1[ch*16+i];
          g[i] = 0.5f*hv*(1.0f + erff(hv*0.70710678118654752f));
        }
        #pragma unroll
        for (int c = 0; c < 64; ++c) {
          const float* w = W2 + c*256 + ch*16;
          float e0=0.f,e1=0.f,e2=0.f,e3=0.f;
          #pragma unroll
          for (int i = 0; i < 16; i += 4) {
            e0 = fmaf(g[i],   w[i],   e0); e1 = fmaf(g[i+1], w[i+1], e1);
            e2 = fmaf(g[i+2], w[i+2], e2); e3 = fmaf(g[i+3], w[i+3], e3);
          }
          ff[c] += (e0+e1)+(e2+e3);
        }
      }
      float sum = 0.f, sq = 0.f;
      #pragma unroll
      for (int c = 0; c < 64; ++c) {
        const float y = xr[c] + ff[c] + Bf2[c];
        ff[c] = y; sum += y; sq = fmaf(y, y, sq);
      }
      const float mean = sum * (1.0f/64.0f);
      const float var  = sq * (1.0f/64.0f) - mean*mean;
      const float rstd = rsqrtf(var + 1e-5f);
      #pragma unroll
      for (int c = 0; c < 64; ++c)
        xr[c] = (ff[c] - mean)*rstd*G2[c] + B2[c];
    }
  }

  // ---- mean over sequence -> nf[b][s][d] ----
  #pragma unroll
  for (int c = 0; c < 64; ++c) tbuf[c*SEQ + t] = __float2half(xr[c]);
  __syncthreads();
  if (t < 64) {
    float sm = 0.f;
    for (int r = 0; r < SEQ; ++r) sm += __half2float(tbuf[t*SEQ + r]);
    nf[((size_t)b*4 + s)*64 + t] = sm * (1.0f/256.0f);
  }
}

// ------------------------- graph head kernel -------------------------
__global__ __launch_bounds__(128) void head_kernel(
  const float* __restrict__ nf,
  const float* __restrict__ ws_w, const float* __restrict__ ws_b,
  const float* __restrict__ b_s,  const float* __restrict__ lambda_init,
  const float* __restrict__ mc_w1, const float* __restrict__ mc_b1,
  const float* __restrict__ mc_w2, const float* __restrict__ mc_b2,
  const float* __restrict__ g1w, const float* __restrict__ g1b,
  const float* __restrict__ g2w, const float* __restrict__ g2b,
  const float* __restrict__ cw1, const float* __restrict__ cb1,
  const float* __restrict__ cw2, const float* __restrict__ cb2,
  float* __restrict__ out)
{
  const int b = blockIdx.x, t = threadIdx.x;
  __shared__ float nfb[256];
  __shared__ float meannf[64];
  __shared__ float fafb[8];
  __shared__ float z1[32];
  __shared__ float normM[16];
  __shared__ float rs[4];
  __shared__ float xw[512];
  __shared__ float hmat[512];
  __shared__ float hw[1024];
  __shared__ float gv[256];
  __shared__ float r1[128];

  for (int i = t; i < 256; i += 128) nfb[i] = nf[b*256 + i];
  __syncthreads();
  if (t < 8) {
    const int i = t & 3;
    const float* w = ws_w + (t >> 2)*64;
    float acc = 0.f;
    for (int c = 0; c < 64; ++c) acc = fmaf(nfb[i*64+c], w[c], acc);
    fafb[t] = acc;                           // fa[0..3], fb[0..3]
  }
  if (t >= 64 && t < 128) {
    const int d = t - 64;
    meannf[d] = 0.25f*(nfb[d] + nfb[64+d] + nfb[128+d] + nfb[192+d]);
  }
  __syncthreads();
  if (t < 32) {
    float acc = mc_b1[t];
    const float* w = mc_w1 + t*64;
    for (int c = 0; c < 64; ++c) acc = fmaf(meannf[c], w[c], acc);
    z1[t] = fmaxf(acc, 0.f);
  }
  __syncthreads();
  if (t == 0) {
    float li = mc_b2[0];
    for (int k = 0; k < 32; ++k) li = fmaf(z1[k], mc_w2[k], li);
    const float lam = (1.0f/(1.0f + __expf(-li))) * lambda_init[0];
    const float AB[4][4] = {{1,1,0,0},{1,1,1,1},{0,1,1,1},{0,1,1,1}};
    const float add = ws_b[0] + b_s[0];
    float sM[4][4], deg[4];
    for (int i = 0; i < 4; ++i) {
      float d_ = 0.f;
      for (int j = 0; j < 4; ++j) {
        sM[i][j] = 1.0f/(1.0f + __expf(-(fafb[i] + fafb[4+j] + add)));
        d_ += sM[i][j];
      }
      deg[i] = d_;
    }
    float A[4][4], deg2[4], dinv[4];
    for (int i = 0; i < 4; ++i)
      for (int j = 0; j < 4; ++j) {
        const float a_ = sM[i][j] / (deg[j] + 1e-8f);
        const float sh = fmaxf(a_ * AB[i][j], 0.f);
        A[i][j] = lam*((i==j) ? 1.f : 0.f) + (1.0f - lam)*sh;
      }
    for (int j = 0; j < 4; ++j) {
      float d_ = 0.f;
      for (int i = 0; i < 4; ++i) d_ += A[i][j];
      deg2[j] = d_;
      dinv[j] = (d_ > 0.f) ? rsqrtf(d_) : 0.f;
    }
    for (int i = 0; i < 4; ++i) {
      float r_ = 0.f;
      for (int j = 0; j < 4; ++j) {
        const float n_ = dinv[i]*A[i][j]*dinv[j];
        normM[i*4+j] = n_;
        r_ += n_;
      }
      rs[i] = r_;
    }
  }
  __syncthreads();
  for (int idx = t; idx < 512; idx += 128) {
    const int i = idx >> 7, f = idx & 127;
    float acc = 0.f;
    for (int c = 0; c < 64; ++c) acc = fmaf(nfb[i*64+c], g1w[c*128 + f], acc);
    xw[idx] = acc;
  }
  __syncthreads();
  for (int idx = t; idx < 512; idx += 128) {
    const int j = idx >> 7, f = idx & 127;
    float acc = g1b[f];
    #pragma unroll
    for (int i = 0; i < 4; ++i) acc = fmaf(normM[i*4+j], xw[i*128+f], acc);
    hmat[j*128+f] = fmaxf(acc, 0.f);
  }
  __syncthreads();
  for (int idx = t; idx < 1024; idx += 128) {
    const int i = idx >> 8, f = idx & 255;
    float acc = 0.f;
    for (int c = 0; c < 128; ++c) acc = fmaf(hmat[i*128+c], g2w[c*256+f], acc);
    hw[idx] = acc;
  }
  __syncthreads();
  for (int f = t; f < 256; f += 128) {
    float acc = 0.f;
    #pragma unroll
    for (int i = 0; i < 4; ++i) acc = fmaf(rs[i], hw[i*256+f], acc);
    gv[f] = 0.25f*acc + g2b[f];
  }
  __syncthreads();
  {
    const int k = t;
    if (k < 128) {
      float acc = cb1[k];
      for (int c = 0; c < 256; ++c) acc = fmaf(gv[c], cw1[c*128+k], acc);
      r1[k] = fmaxf(acc, 0.f);
    }
  }
  __syncthreads();
  if (t < 5) {
    float acc = cb2[t];
    for (int k = 0; k < 128; ++k) acc = fmaf(r1[k], cw2[k*5 + t], acc);
    out[b*5 + t] = acc;
  }
}

// ------------------------- launch -------------------------
extern "C" void kernel_launch(void* const* d_in, const int* in_sizes, int n_in,
                              void* d_out, int out_size, void* d_ws, size_t ws_size,
                              hipStream_t stream) {
  (void)in_sizes; (void)n_in; (void)out_size; (void)ws_size;
  const float* sens   = (const float*)d_in[0];
  const float* c1w    = (const float*)d_in[1];
  const float* c1b    = (const float*)d_in[2];
  const float* bn1g   = (const float*)d_in[3];
  const float* bn1b   = (const float*)d_in[4];
  const float* c2w    = (const float*)d_in[5];
  const float* c2b    = (const float*)d_in[6];
  const float* bn2g   = (const float*)d_in[7];
  const float* bn2b   = (const float*)d_in[8];
  const float* wqkv   = (const float*)d_in[9];
  const float* bqkv   = (const float*)d_in[10];
  const float* wo     = (const float*)d_in[11];
  const float* bo     = (const float*)d_in[12];
  const float* ln1g   = (const float*)d_in[13];
  const float* ln1b   = (const float*)d_in[14];
  const float* fw1    = (const float*)d_in[15];
  const float* fb1    = (const float*)d_in[16];
  const float* fw2    = (const float*)d_in[17];
  const float* fb2    = (const float*)d_in[18];
  const float* ln2g   = (const float*)d_in[19];
  const float* ln2b   = (const float*)d_in[20];
  const float* ws_w   = (const float*)d_in[21];
  const float* ws_b   = (const float*)d_in[22];
  const float* b_s    = (const float*)d_in[23];
  const float* lam0   = (const float*)d_in[24];
  const float* mc_w1  = (const float*)d_in[25];
  const float* mc_b1  = (const float*)d_in[26];
  const float* mc_w2  = (const float*)d_in[27];
  const float* mc_b2  = (const float*)d_in[28];
  const float* g1w    = (const float*)d_in[29];
  const float* g1b    = (const float*)d_in[30];
  const float* g2w    = (const float*)d_in[31];
  const float* g2b    = (const float*)d_in[32];
  const float* cw1    = (const float*)d_in[33];
  const float* cb1    = (const float*)d_in[34];
  const float* cw2    = (const float*)d_in[35];
  const float* cb2    = (const float*)d_in[36];

  float* x0 = (float*)d_ws;                                      // 4*64*256*64 f32 = 16 MiB
  float* nf = (float*)((char*)d_ws + (size_t)NSENS*NB*SEQ*DM*4); // 64*4*64 f32

  conv_kernel<<<NSENS*NB, 256, 0, stream>>>(sens, c1w, c1b, bn1g, bn1b,
                                            c2w, c2b, bn2g, bn2b, x0);
  tx_kernel<<<NSENS*NB, 256, 0, stream>>>(x0, nf, wqkv, bqkv, wo, bo,
                                          ln1g, ln1b, fw1, fb1, fw2, fb2, ln2g, ln2b);
  head_kernel<<<NB, 128, 0, stream>>>(nf, ws_w, ws_b, b_s, lam0,
                                      mc_w1, mc_b1, mc_w2, mc_b2,
                                      g1w, g1b, g2w, g2b, cw1, cb1, cw2, cb2,
                                      (float*)d_out);
}